// Round 3
// baseline (297.066 us; speedup 1.0000x reference)
//
#include <hip/hip_runtime.h>
#include <hip/hip_bf16.h>

// Gather: out[row, :] = features[rules[row], :], C = 64 floats (256 B/row).
//
// R3 = R2 kernel, launched 4x (idempotent) as a TIMING PROBE:
// (dur_us_R3 - dur_us_R2)/3 = true per-kernel duration, separating kernel
// time from the ~160 us of harness poison-fill/restore overhead that
// dominates dur_us (rocprof top-5 is all 82-us fillBuffer dispatches; our
// kernel is <78 us and invisible). If the kernel is >=78 us, its 4 copies
// will also surface in the rocprof top-5 with their own counters.

typedef float f4 __attribute__((ext_vector_type(4)));

#define BLOCK 256
#define ROWS_PER_BLOCK 256
#define C_F4 16            // 64 floats = 16 float4
#define ROWS_PER_THREAD 16 // ROWS_PER_BLOCK / (BLOCK / C_F4)

__global__ __launch_bounds__(BLOCK) void BLOutputLayer_gather_kernel(
    const f4* __restrict__ features,   // [N_ACTIVE, 16] as float4
    const int* __restrict__ rules,     // [N_ROWS]
    f4* __restrict__ out,              // [N_ROWS, 16] as float4
    int n_rows) {
    __shared__ int lds_rules[ROWS_PER_BLOCK];

    const int t    = threadIdx.x;
    const int base = blockIdx.x * ROWS_PER_BLOCK;

    {
        const int r = base + t;
        lds_rules[t] = (r < n_rows) ? rules[r] : 0;
    }
    __syncthreads();

    const int lane = t & (C_F4 - 1);   // float4 index within a row
    const int g    = t >> 4;           // row-group 0..15

    if (base + ROWS_PER_BLOCK <= n_rows) {
        int src[ROWS_PER_THREAD];
#pragma unroll
        for (int j = 0; j < ROWS_PER_THREAD; ++j)
            src[j] = lds_rules[g + C_F4 * j];

        f4 v[ROWS_PER_THREAD];
#pragma unroll
        for (int j = 0; j < ROWS_PER_THREAD; ++j)   // 16 independent loads in flight
            v[j] = features[(size_t)src[j] * C_F4 + lane];

#pragma unroll
        for (int j = 0; j < ROWS_PER_THREAD; ++j) {
            const int row = base + g + C_F4 * j;
            __builtin_nontemporal_store(v[j], &out[(size_t)row * C_F4 + lane]);
        }
    } else {
        for (int j = 0; j < ROWS_PER_THREAD; ++j) {
            const int row = base + g + C_F4 * j;
            if (row < n_rows) {
                const int s = lds_rules[g + C_F4 * j];
                out[(size_t)row * C_F4 + lane] = features[(size_t)s * C_F4 + lane];
            }
        }
    }
}

extern "C" void kernel_launch(void* const* d_in, const int* in_sizes, int n_in,
                              void* d_out, int out_size, void* d_ws, size_t ws_size,
                              hipStream_t stream) {
    const f4*  features = (const f4*)d_in[0];
    const int* rules    = (const int*)d_in[1];
    f4*        out      = (f4*)d_out;

    const int n_rows = in_sizes[1];                          // 524288
    const int grid   = (n_rows + ROWS_PER_BLOCK - 1) / ROWS_PER_BLOCK;  // 2048

    // 4 identical launches: timing probe (see header comment). Idempotent.
    for (int i = 0; i < 4; ++i)
        BLOutputLayer_gather_kernel<<<grid, BLOCK, 0, stream>>>(features, rules, out, n_rows);
}

// Round 4
// 181.407 us; speedup vs baseline: 1.6376x; 1.6376x over previous
//
#include <hip/hip_runtime.h>
#include <hip/hip_bf16.h>

// Gather: out[row, :] = features[rules[row], :], C = 64 floats (256 B/row).
//
// Measured (R3 4x-launch probe): kernel ~38 us vs ~29.4 us pure-stream
// roofline (185 MB HBM: 51 MB compulsory reads + 134 MB writes) -> within
// ~15-25% of the achievable mixed read/write bound. R1 (no ILP) vs R2
// (16-deep ILP) differ by only ~5% -> memory-bound plateau, not latency.
// dur_us is dominated by ~145 us fixed harness overhead (82 us poison fill
// + input restore), so this is near the controllable limit.
//
// Structure: 256 rows/block, rules staged via LDS (coalesced, NT load),
// each thread owns one float4 lane x 16 rows, 16 independent feature loads
// in flight, fully-coalesced NT stores (1 KiB contiguous per wave-store).

typedef float f4 __attribute__((ext_vector_type(4)));

#define BLOCK 256
#define ROWS_PER_BLOCK 256
#define C_F4 16            // 64 floats = 16 float4
#define ROWS_PER_THREAD 16 // ROWS_PER_BLOCK / (BLOCK / C_F4)

__global__ __launch_bounds__(BLOCK) void BLOutputLayer_gather_kernel(
    const f4* __restrict__ features,   // [N_ACTIVE, 16] as float4
    const int* __restrict__ rules,     // [N_ROWS]
    f4* __restrict__ out,              // [N_ROWS, 16] as float4
    int n_rows) {
    __shared__ int lds_rules[ROWS_PER_BLOCK];

    const int t    = threadIdx.x;
    const int base = blockIdx.x * ROWS_PER_BLOCK;

    // Stage this block's rule indices (coalesced; rules are streamed once,
    // so bypass-cache hint on the load).
    {
        const int r = base + t;
        lds_rules[t] = (r < n_rows) ? __builtin_nontemporal_load(&rules[r]) : 0;
    }
    __syncthreads();

    const int lane = t & (C_F4 - 1);   // float4 index within a row
    const int g    = t >> 4;           // row-group 0..15

    if (base + ROWS_PER_BLOCK <= n_rows) {
        int src[ROWS_PER_THREAD];
#pragma unroll
        for (int j = 0; j < ROWS_PER_THREAD; ++j)
            src[j] = lds_rules[g + C_F4 * j];

        f4 v[ROWS_PER_THREAD];
#pragma unroll
        for (int j = 0; j < ROWS_PER_THREAD; ++j)   // 16 independent loads in flight
            v[j] = features[(size_t)src[j] * C_F4 + lane];

#pragma unroll
        for (int j = 0; j < ROWS_PER_THREAD; ++j) {
            const int row = base + g + C_F4 * j;
            __builtin_nontemporal_store(v[j], &out[(size_t)row * C_F4 + lane]);
        }
    } else {
        for (int j = 0; j < ROWS_PER_THREAD; ++j) {
            const int row = base + g + C_F4 * j;
            if (row < n_rows) {
                const int s = lds_rules[g + C_F4 * j];
                out[(size_t)row * C_F4 + lane] = features[(size_t)s * C_F4 + lane];
            }
        }
    }
}

extern "C" void kernel_launch(void* const* d_in, const int* in_sizes, int n_in,
                              void* d_out, int out_size, void* d_ws, size_t ws_size,
                              hipStream_t stream) {
    const f4*  features = (const f4*)d_in[0];
    const int* rules    = (const int*)d_in[1];
    f4*        out      = (f4*)d_out;

    const int n_rows = in_sizes[1];                          // 524288
    const int grid   = (n_rows + ROWS_PER_BLOCK - 1) / ROWS_PER_BLOCK;  // 2048

    BLOutputLayer_gather_kernel<<<grid, BLOCK, 0, stream>>>(features, rules, out, n_rows);
}